// Round 2
// baseline (27825.348 us; speedup 1.0000x reference)
//
#include <hip/hip_runtime.h>
#include <hip/hip_bf16.h>

#define LSEQ  1024
#define DEPTH 4
#define NTILE 97

typedef __attribute__((ext_vector_type(8))) short short8;
typedef __attribute__((ext_vector_type(4))) float f32x4;

__device__ __forceinline__ short f2bf(float f) {
    unsigned u = __builtin_bit_cast(unsigned, f);
    u += 0x7fffu + ((u >> 16) & 1u);
    return (short)(u >> 16);
}
__device__ __forceinline__ float sigm(float x) { return __fdividef(1.f, 1.f + __expf(-x)); }
__device__ __forceinline__ void st32f(int* p, int v) { __hip_atomic_store(p, v, __ATOMIC_RELAXED, __HIP_MEMORY_SCOPE_AGENT); }
__device__ __forceinline__ int  ld32f(const int* p) { return __hip_atomic_load(p, __ATOMIC_RELAXED, __HIP_MEMORY_SCOPE_AGENT); }
__device__ __forceinline__ void st64g(unsigned long long* p, unsigned long long v) { __hip_atomic_store(p, v, __ATOMIC_RELAXED, __HIP_MEMORY_SCOPE_AGENT); }
__device__ __forceinline__ unsigned long long ld64g(const unsigned long long* p) { return __hip_atomic_load(p, __ATOMIC_RELAXED, __HIP_MEMORY_SCOPE_AGENT); }

extern "C" __global__ void __launch_bounds__(1024)
ctlstm_kernel(const float* __restrict__ x, const float* __restrict__ td,
              const float* __restrict__ Wi, const float* __restrict__ bi,
              const float* __restrict__ Wf, const float* __restrict__ bf,
              const float* __restrict__ Wie, const float* __restrict__ bie,
              const float* __restrict__ Wfe, const float* __restrict__ bfe,
              const float* __restrict__ Wz, const float* __restrict__ bz,
              const float* __restrict__ Wo, const float* __restrict__ bo,
              const float* __restrict__ Wd, const float* __restrict__ bdp,
              const float* __restrict__ betap,
              float* __restrict__ out,
              int* __restrict__ pflags, int* __restrict__ cflags,
              float* __restrict__ ring)
{
    const int tid  = threadIdx.x;
    const int w    = tid >> 6;
    const int lane = tid & 63;
    const int l16  = lane & 15;
    const int lhi  = lane >> 4;

    if (blockIdx.x < 4) {
        // ================= CONSUMER: one block per batch-group =================
        const int g = blockIdx.x;
        __shared__ float g_lds[6][16][16][17];     // [gate][jtile][row][col] padded
        __shared__ __align__(16) unsigned short h_lds[16 * 256];  // swizzled bf16
        __shared__ float dvals[16];

        // zero h LDS (1024 ull = exactly one per thread)
        ((unsigned long long*)h_lds)[tid] = 0ull;

        const float beta = betap[0];
        const int nt = (w == 15) ? 7 : 6;

        // ---- resident W fragments (h-part: rows 256..511) ----
        short8 wfrag[7][8];
        #pragma unroll
        for (int i = 0; i < 7; ++i) {
            if (i < nt) {
                const int ct = (i < 6) ? (w * 6 + i) : 96;
                if (ct == 96) {
                    #pragma unroll
                    for (int kk = 0; kk < 8; ++kk) {
                        short8 f;
                        #pragma unroll
                        for (int e = 0; e < 8; ++e) {
                            const int k = kk * 32 + lhi * 8 + e;
                            f[e] = (l16 == 0) ? f2bf(Wd[256 + k]) : (short)0;
                        }
                        wfrag[i][kk] = f;
                    }
                } else {
                    const int gate = ct >> 4, jt = ct & 15;
                    const float* Wg = (gate == 0) ? Wi : (gate == 1) ? Wf : (gate == 2) ? Wie
                                    : (gate == 3) ? Wfe : (gate == 4) ? Wz : Wo;
                    const int col = jt * 16 + l16;
                    #pragma unroll
                    for (int kk = 0; kk < 8; ++kk) {
                        short8 f;
                        #pragma unroll
                        for (int e = 0; e < 8; ++e) {
                            const int k = kk * 32 + lhi * 8 + e;
                            f[e] = f2bf(Wg[(256 + k) * 256 + col]);
                        }
                        wfrag[i][kk] = f;
                    }
                }
            }
        }

        // carried state: this wave = batch row (g*16 + w); lane owns j = lane*4..+3
        float cC[4] = {0.f, 0.f, 0.f, 0.f};
        float ceS[4] = {0.f, 0.f, 0.f, 0.f};
        f32x4 hreg = {0.f, 0.f, 0.f, 0.f};
        const long long brow = (long long)(g * 16 + w);

        // prologue: wait until producers finished steps 0 and 1
        {
            int v = (lane < 8) ? ld32f(&pflags[lane * 32]) : 0x7fffffff;
            while (__any(v < 2)) {
                __builtin_amdgcn_s_sleep(8);
                v = (lane < 8) ? ld32f(&pflags[lane * 32]) : 0x7fffffff;
            }
        }
        f32x4 gx[7];
        #pragma unroll
        for (int i = 0; i < 7; ++i) {
            if (i < nt) {
                const int ct = (i < 6) ? (w * 6 + i) : 96;
                const unsigned long long* p =
                    (const unsigned long long*)&ring[((0 * 4 + g) * NTILE + ct) * 256 + lane * 4];
                union { unsigned long long q[2]; f32x4 v; } u;
                u.q[0] = ld64g(p); u.q[1] = ld64g(p + 1);
                gx[i] = u.v;
            }
        }
        __syncthreads();

        for (int t = 0; t < LSEQ; ++t) {
            // ---------- phase A: GEMM (h-part) + activations ----------
            f32x4 acc[7];
            #pragma unroll
            for (int i = 0; i < 7; ++i) if (i < nt) acc[i] = gx[i];

            short8 hf[8];
            #pragma unroll
            for (int kk = 0; kk < 8; ++kk) {
                const int byteoff = l16 * 512 + ((kk * 64 + lhi * 16) ^ ((l16 & 7) << 4));
                hf[kk] = *(const short8*)((const char*)h_lds + byteoff);
            }
            #pragma unroll
            for (int kk = 0; kk < 8; ++kk) {
                #pragma unroll
                for (int i = 0; i < 7; ++i)
                    if (i < nt)
                        acc[i] = __builtin_amdgcn_mfma_f32_16x16x32_bf16(hf[kk], wfrag[i][kk], acc[i], 0, 0, 0);
            }

            #pragma unroll
            for (int i = 0; i < 6; ++i) {
                const int ct = w * 6 + i, gate = ct >> 4, jt = ct & 15;
                #pragma unroll
                for (int q = 0; q < 4; ++q) {
                    float v = acc[i][q];
                    v = (gate == 4) ? (1.f - 2.f * __fdividef(1.f, 1.f + __expf(v))) : sigm(v);
                    g_lds[gate][jt][lhi * 4 + q][l16] = v;
                }
            }
            if (nt == 7 && l16 == 0) {   // delta head (wave 15, 4 lanes cover 16 rows)
                #pragma unroll
                for (int q = 0; q < 4; ++q) {
                    const float gv = acc[6][q];
                    const float bg_ = beta * gv;
                    const float sp = fmaxf(bg_, 0.f) + __logf(1.f + __expf(-fabsf(bg_)));
                    dvals[lhi * 4 + q] = __fdividef(sp, beta);
                }
            }
            __syncthreads();   // B1: gates ready; all waves consumed gx[t]

            // ---------- phase B: publish, prefetch, state update ----------
            if (w == 0 && lane == 0) st32f(&cflags[g * 32], t + 1);
            int v8 = 0x7fffffff;
            if (t + 2 < LSEQ && lane < 8) v8 = ld32f(&pflags[lane * 32]);  // early issue
            if (t + 1 < LSEQ) {
                const int slot = (t + 1) & (DEPTH - 1);
                #pragma unroll
                for (int i = 0; i < 7; ++i) {
                    if (i < nt) {
                        const int ct = (i < 6) ? (w * 6 + i) : 96;
                        const unsigned long long* p =
                            (const unsigned long long*)&ring[((slot * 4 + g) * NTILE + ct) * 256 + lane * 4];
                        union { unsigned long long q[2]; f32x4 v; } u;
                        u.q[0] = ld64g(p); u.q[1] = ld64g(p + 1);
                        gx[i] = u.v;
                    }
                }
            }

            // update (this wave = row w of the group)
            const int jt_u = lane >> 2, c0 = (lane & 3) * 4;
            float ig[4], fg[4], ieg[4], feg[4], zg[4], og[4];
            #pragma unroll
            for (int q = 0; q < 4; ++q) {
                ig[q]  = g_lds[0][jt_u][w][c0 + q];
                fg[q]  = g_lds[1][jt_u][w][c0 + q];
                ieg[q] = g_lds[2][jt_u][w][c0 + q];
                feg[q] = g_lds[3][jt_u][w][c0 + q];
                zg[q]  = g_lds[4][jt_u][w][c0 + q];
                og[q]  = g_lds[5][jt_u][w][c0 + q];
            }
            const float dn = dvals[w];
            float cs[4], ceN[4];
            #pragma unroll
            for (int q = 0; q < 4; ++q) {
                cs[q]  = fg[q] * cC[q] + ig[q] * zg[q];
                ceN[q] = feg[q] * ceS[q] + ieg[q] * zg[q];
            }
            *(f32x4*)(out + (brow * LSEQ + t) * 256 + lane * 4) = hreg;

            if (t + 1 < LSEQ) {
                const float dtv = td[brow * LSEQ + (t + 1)];
                const float e = __expf(-dn * dtv);
                unsigned long long pk = 0;
                #pragma unroll
                for (int q = 0; q < 4; ++q) {
                    const float c = cs[q] + (ceN[q] - cs[q]) * e;
                    cC[q] = c;
                    const float hv = og[q] * (1.f - 2.f * __fdividef(1.f, 1.f + __expf(2.f * c)));
                    hreg[q] = hv;
                    pk |= ((unsigned long long)(unsigned short)f2bf(hv)) << (16 * q);
                }
                *(unsigned long long*)((char*)h_lds + (w * 512 + ((lane * 8) ^ ((w & 7) << 4)))) = pk;
                #pragma unroll
                for (int q = 0; q < 4; ++q) ceS[q] = ceN[q];
                if (t + 2 < LSEQ) {   // late verify: Gx[t+2]'s slot fully written?
                    while (__any(v8 < t + 3)) {
                        __builtin_amdgcn_s_sleep(8);
                        v8 = (lane < 8) ? ld32f(&pflags[lane * 32]) : 0x7fffffff;
                    }
                }
            } else {
                float* so = out + (long long)64 * LSEQ * 256 + brow * 769;
                #pragma unroll
                for (int q = 0; q < 4; ++q) {
                    const int jj = lane * 4 + q;
                    so[jj]       = og[q];
                    so[256 + jj] = cs[q];
                    so[512 + jj] = ceN[q];
                }
                if (lane == 0) so[768] = dn;
            }
            __syncthreads();   // B2: h(t+1) in LDS
        }
    } else {
        // ================= PRODUCER: Gx[t] = x_t @ Wx + b into ring =================
        const int p  = blockIdx.x - 4;          // 0..7
        const int r  = w & 3;                    // row-group
        const int q4 = w >> 2;                   // tile quarter
        const int base_ct = p * 12 + q4 * 3;
        const int cnt = (p == 7 && q4 == 3) ? 4 : 3;

        short8 wx[4][8];
        float bias[4] = {0.f, 0.f, 0.f, 0.f};
        #pragma unroll
        for (int i = 0; i < 4; ++i) {
            if (i < cnt) {
                const int ct = base_ct + i;
                if (ct == 96) {
                    bias[i] = (l16 == 0) ? bdp[0] : 0.f;
                    #pragma unroll
                    for (int kk = 0; kk < 8; ++kk) {
                        short8 f;
                        #pragma unroll
                        for (int e = 0; e < 8; ++e) {
                            const int k = kk * 32 + lhi * 8 + e;
                            f[e] = (l16 == 0) ? f2bf(Wd[k]) : (short)0;
                        }
                        wx[i][kk] = f;
                    }
                } else {
                    const int gate = ct >> 4, jt = ct & 15;
                    const float* Wg = (gate == 0) ? Wi : (gate == 1) ? Wf : (gate == 2) ? Wie
                                    : (gate == 3) ? Wfe : (gate == 4) ? Wz : Wo;
                    const float* bg = (gate == 0) ? bi : (gate == 1) ? bf : (gate == 2) ? bie
                                    : (gate == 3) ? bfe : (gate == 4) ? bz : bo;
                    const int col = jt * 16 + l16;
                    bias[i] = bg[col];
                    #pragma unroll
                    for (int kk = 0; kk < 8; ++kk) {
                        short8 f;
                        #pragma unroll
                        for (int e = 0; e < 8; ++e) {
                            const int k = kk * 32 + lhi * 8 + e;
                            f[e] = f2bf(Wg[k * 256 + col]);
                        }
                        wx[i][kk] = f;
                    }
                }
            }
        }

        const long long b = (long long)(r * 16 + l16);
        for (int t = 0; t < LSEQ; ++t) {
            if (t >= DEPTH) {   // back-pressure
                int v = (lane < 4) ? ld32f(&cflags[lane * 32]) : 0x7fffffff;
                while (__any(v < t - (DEPTH - 1))) {
                    __builtin_amdgcn_s_sleep(16);
                    v = (lane < 4) ? ld32f(&cflags[lane * 32]) : 0x7fffffff;
                }
            }
            const float* xp = x + (b * LSEQ + t) * 256;
            short8 af[8];
            #pragma unroll
            for (int kk = 0; kk < 8; ++kk) {
                f32x4 a = *(const f32x4*)(xp + kk * 32 + lhi * 8);
                f32x4 c = *(const f32x4*)(xp + kk * 32 + lhi * 8 + 4);
                short8 f;
                #pragma unroll
                for (int e = 0; e < 4; ++e) { f[e] = f2bf(a[e]); f[4 + e] = f2bf(c[e]); }
                af[kk] = f;
            }
            f32x4 acc[4];
            #pragma unroll
            for (int i = 0; i < 4; ++i)
                if (i < cnt) acc[i] = f32x4{bias[i], bias[i], bias[i], bias[i]};
            #pragma unroll
            for (int kk = 0; kk < 8; ++kk) {
                #pragma unroll
                for (int i = 0; i < 4; ++i)
                    if (i < cnt)
                        acc[i] = __builtin_amdgcn_mfma_f32_16x16x32_bf16(af[kk], wx[i][kk], acc[i], 0, 0, 0);
            }
            const int slot = t & (DEPTH - 1);
            #pragma unroll
            for (int i = 0; i < 4; ++i) {
                if (i < cnt) {
                    const int ct = base_ct + i;
                    unsigned long long* pp =
                        (unsigned long long*)&ring[((slot * 4 + r) * NTILE + ct) * 256 + lane * 4];
                    union { unsigned long long q[2]; f32x4 v; } u;
                    u.v = acc[i];
                    st64g(pp, u.q[0]); st64g(pp + 1, u.q[1]);
                }
            }
            asm volatile("s_waitcnt vmcnt(0)" ::: "memory");
            __syncthreads();
            if (tid == 0) st32f(&pflags[p * 32], t + 1);
        }
    }
}

extern "C" void kernel_launch(void* const* d_in, const int* in_sizes, int n_in,
                              void* d_out, int out_size, void* d_ws, size_t ws_size,
                              hipStream_t stream) {
    const float* x   = (const float*)d_in[0];
    const float* td  = (const float*)d_in[1];
    const float* Wi  = (const float*)d_in[2];
    const float* bi  = (const float*)d_in[3];
    const float* Wf  = (const float*)d_in[4];
    const float* bf  = (const float*)d_in[5];
    const float* Wie = (const float*)d_in[6];
    const float* bie = (const float*)d_in[7];
    const float* Wfe = (const float*)d_in[8];
    const float* bfe = (const float*)d_in[9];
    const float* Wz  = (const float*)d_in[10];
    const float* bz  = (const float*)d_in[11];
    const float* Wo  = (const float*)d_in[12];
    const float* bo  = (const float*)d_in[13];
    const float* Wd  = (const float*)d_in[14];
    const float* bd  = (const float*)d_in[15];
    const float* be  = (const float*)d_in[16];

    int* pflags = (int*)d_ws;                            // 8 flags * 128 B
    int* cflags = (int*)((char*)d_ws + 4096);            // 4 flags * 128 B
    float* ring = (float*)((char*)d_ws + 8192);          // 4*4*97*256 f32 ≈ 1.6 MB

    hipMemsetAsync(d_ws, 0, 8192, stream);
    hipLaunchKernelGGL(ctlstm_kernel, dim3(12), dim3(1024), 0, stream,
                       x, td, Wi, bi, Wf, bf, Wie, bie, Wfe, bfe, Wz, bz, Wo, bo,
                       Wd, bd, be, (float*)d_out, pflags, cflags, ring);
}

// Round 4
// 5729.031 us; speedup vs baseline: 4.8569x; 4.8569x over previous
//
#include <hip/hip_runtime.h>
#include <hip/hip_bf16.h>

#define LSEQ  1024
#define DEPTH 4

typedef __attribute__((ext_vector_type(8))) short short8;
typedef __attribute__((ext_vector_type(4))) float f32x4;

static __device__ __forceinline__ short f2bf(float f) {
    unsigned u = __builtin_bit_cast(unsigned, f);
    u += 0x7fffu + ((u >> 16) & 1u);
    return (short)(u >> 16);
}
static __device__ __forceinline__ float sigm(float x) { return __fdividef(1.f, 1.f + __expf(-x)); }
// tanh(g/2) = 2*sigmoid(g)-1
static __device__ __forceinline__ float tanh2(float g) { return 1.f - 2.f * __fdividef(1.f, 1.f + __expf(g)); }

static __device__ __forceinline__ void st32f(int* p, int v) { __hip_atomic_store(p, v, __ATOMIC_RELAXED, __HIP_MEMORY_SCOPE_AGENT); }
static __device__ __forceinline__ int  ld32f(const int* p) { return __hip_atomic_load(p, __ATOMIC_RELAXED, __HIP_MEMORY_SCOPE_AGENT); }
static __device__ __forceinline__ void st64g(unsigned long long* p, unsigned long long v) { __hip_atomic_store(p, v, __ATOMIC_RELAXED, __HIP_MEMORY_SCOPE_AGENT); }
static __device__ __forceinline__ unsigned long long ld64g(const unsigned long long* p) { return __hip_atomic_load(p, __ATOMIC_RELAXED, __HIP_MEMORY_SCOPE_AGENT); }

extern "C" __global__ void __launch_bounds__(512, 2)
ctlstm_kernel(const float* __restrict__ x, const float* __restrict__ td,
              const float* __restrict__ Wi, const float* __restrict__ bi,
              const float* __restrict__ Wf, const float* __restrict__ bf,
              const float* __restrict__ Wie, const float* __restrict__ bie,
              const float* __restrict__ Wfe, const float* __restrict__ bfe,
              const float* __restrict__ Wz, const float* __restrict__ bz,
              const float* __restrict__ Wo, const float* __restrict__ bo,
              const float* __restrict__ Wd, const float* __restrict__ bdp,
              const float* __restrict__ betap,
              float* __restrict__ out,
              int* __restrict__ pflags, int* __restrict__ cflags,
              int* __restrict__ hflags, float* __restrict__ ring,
              unsigned short* __restrict__ hbuf)
{
    const int tid  = threadIdx.x;
    const int w    = tid >> 6;      // wave 0..7
    const int lane = tid & 63;
    const int l16  = lane & 15;
    const int lhi  = lane >> 4;

    if (blockIdx.x < 16) {
        // ===================== CONSUMER block (g, c) =====================
        const int g = blockIdx.x >> 2;
        const int c = blockIdx.x & 3;

        __shared__ float g_lds[24][16][18];                     // [T=gt*4+jt][row][col]
        __shared__ __align__(16) unsigned short h_lds[16 * 256]; // 8 KB, XOR-swizzled rows
        __shared__ float dvals[16];

        ((unsigned long long*)h_lds)[tid]       = 0ull;
        ((unsigned long long*)h_lds)[tid + 512] = 0ull;

        const float beta = betap[0];

        // ---- resident weight fragments (h-part, rows 256..511) ----
        short8 wfrag[4][8];
        #pragma unroll
        for (int i = 0; i < 4; ++i) {
            const bool hav = (i < 3) || (w == 7);
            if (hav) {
                if (i == 3) {
                    #pragma unroll
                    for (int kk = 0; kk < 8; ++kk) {
                        short8 f;
                        #pragma unroll
                        for (int e = 0; e < 8; ++e)
                            f[e] = (l16 == 0) ? f2bf(Wd[256 + kk * 32 + lhi * 8 + e]) : (short)0;
                        wfrag[i][kk] = f;
                    }
                } else {
                    const int T = w * 3 + i, gt = T >> 2, jt = T & 3;
                    const float* Wg;
                    switch (gt) {
                        case 0: Wg = Wi;  break;
                        case 1: Wg = Wf;  break;
                        case 2: Wg = Wie; break;
                        case 3: Wg = Wfe; break;
                        case 4: Wg = Wz;  break;
                        default: Wg = Wo; break;
                    }
                    const int col = c * 64 + jt * 16 + l16;
                    #pragma unroll
                    for (int kk = 0; kk < 8; ++kk) {
                        short8 f;
                        #pragma unroll
                        for (int e = 0; e < 8; ++e)
                            f[e] = f2bf(Wg[(256 + kk * 32 + lhi * 8 + e) * 256 + col]);
                        wfrag[i][kk] = f;
                    }
                }
            }
        }

        // update-phase mapping: this thread owns (row urow, cols c*64+2*up..+1)
        const int urow = tid >> 5;
        const int up   = tid & 31;
        float cC[2]  = {0.f, 0.f};
        float ceS[2] = {0.f, 0.f};
        float h2[2]  = {0.f, 0.f};

        f32x4 gx[4];
        auto load_gx = [&](int slot) {
            #pragma unroll
            for (int i = 0; i < 4; ++i) {
                const bool hav = (i < 3) || (w == 7);
                if (hav) {
                    const int T  = w * 3 + i;
                    const int ct = (i == 3) ? 96 : ((T >> 2) * 16 + c * 4 + (T & 3));
                    const unsigned long long* pp =
                        (const unsigned long long*)&ring[((size_t)(slot * 4 + g) * 97 + ct) * 256 + lane * 4];
                    union { unsigned long long q[2]; f32x4 v; } u;
                    u.q[0] = ld64g(pp); u.q[1] = ld64g(pp + 1);
                    gx[i] = u.v;
                }
            }
        };

        // prologue: producers must have finished steps 0 and 1
        {
            const int pidx = (lane & 3) * 4 + g;
            int v = (lane < 4) ? ld32f(&pflags[pidx * 32]) : 0x7fffffff;
            while (__any(v < 2)) {
                __builtin_amdgcn_s_sleep(8);
                v = (lane < 4) ? ld32f(&pflags[pidx * 32]) : 0x7fffffff;
            }
        }
        load_gx(0);
        __syncthreads();

        for (int t = 0; t < LSEQ; ++t) {
            // ---------------- phase G: recurrent GEMM + activations ----------------
            short8 hf[8];
            #pragma unroll
            for (int kk = 0; kk < 8; ++kk) {
                const int bo = l16 * 512 + ((kk * 64 + lhi * 16) ^ ((l16 & 7) << 4));
                hf[kk] = *(const short8*)((const char*)h_lds + bo);
            }
            f32x4 acc[4];
            #pragma unroll
            for (int i = 0; i < 4; ++i)
                if ((i < 3) || (w == 7)) acc[i] = gx[i];
            #pragma unroll
            for (int kk = 0; kk < 8; ++kk) {
                #pragma unroll
                for (int i = 0; i < 4; ++i)
                    if ((i < 3) || (w == 7))
                        acc[i] = __builtin_amdgcn_mfma_f32_16x16x32_bf16(hf[kk], wfrag[i][kk], acc[i], 0, 0, 0);
            }
            #pragma unroll
            for (int i = 0; i < 3; ++i) {
                const int T = w * 3 + i, gt = T >> 2;
                #pragma unroll
                for (int q = 0; q < 4; ++q) {
                    float v = acc[i][q];
                    v = (gt == 4) ? tanh2(v) : sigm(v);
                    g_lds[T][lhi * 4 + q][l16] = v;
                }
            }
            if (w == 7 && l16 == 0) {
                #pragma unroll
                for (int q = 0; q < 4; ++q) {
                    const float bg_ = beta * acc[3][q];
                    const float sp  = fmaxf(bg_, 0.f) + __logf(1.f + __expf(-fabsf(bg_)));
                    dvals[lhi * 4 + q] = __fdividef(sp, beta);
                }
            }
            __syncthreads();   // bar1: gates ready

            // ---------------- phase U: state update (own 64-col slice) ----------------
            {
                const int jtl = up >> 3;
                const int cc2 = (up & 7) * 2;
                const float2 iv  = *(const float2*)&g_lds[0 * 4 + jtl][urow][cc2];
                const float2 fv  = *(const float2*)&g_lds[1 * 4 + jtl][urow][cc2];
                const float2 iev = *(const float2*)&g_lds[2 * 4 + jtl][urow][cc2];
                const float2 fev = *(const float2*)&g_lds[3 * 4 + jtl][urow][cc2];
                const float2 zv  = *(const float2*)&g_lds[4 * 4 + jtl][urow][cc2];
                const float2 ov  = *(const float2*)&g_lds[5 * 4 + jtl][urow][cc2];
                const float dn = dvals[urow];

                // outputs[:, t, :] = h(t)
                *(float2*)(out + ((size_t)(g * 16 + urow) * LSEQ + t) * 256 + c * 64 + up * 2)
                    = make_float2(h2[0], h2[1]);

                const float cs0 = fv.x * cC[0] + iv.x * zv.x;
                const float cs1 = fv.y * cC[1] + iv.y * zv.y;
                const float ce0 = fev.x * ceS[0] + iev.x * zv.x;
                const float ce1 = fev.y * ceS[1] + iev.y * zv.y;

                if (t + 1 < LSEQ) {
                    const float dtv = td[(size_t)(g * 16 + urow) * LSEQ + (t + 1)];
                    const float e   = __expf(-dn * dtv);
                    const float cn0 = cs0 + (ce0 - cs0) * e;
                    const float cn1 = cs1 + (ce1 - cs1) * e;
                    const float hv0 = ov.x * tanh2(2.f * cn0);
                    const float hv1 = ov.y * tanh2(2.f * cn1);
                    cC[0] = cn0; cC[1] = cn1;
                    ceS[0] = ce0; ceS[1] = ce1;
                    h2[0] = hv0; h2[1] = hv1;
                    const unsigned pk = (unsigned)(unsigned short)f2bf(hv0)
                                      | ((unsigned)(unsigned short)f2bf(hv1) << 16);
                    const int par = (t + 1) & 1;
                    st32f((int*)&hbuf[((((size_t)par * 4 + g) * 4 + c) * 16 + urow) * 64 + up * 2], (int)pk);
                    const int lin = c * 128 + up * 4;
                    *(unsigned*)((char*)h_lds + urow * 512 + (lin ^ ((urow & 7) << 4))) = pk;
                } else {
                    float* so = out + (size_t)64 * LSEQ * 256 + (size_t)(g * 16 + urow) * 769;
                    const int jj = c * 64 + up * 2;
                    so[jj]           = ov.x; so[jj + 1]       = ov.y;
                    so[256 + jj]     = cs0;  so[256 + jj + 1] = cs1;
                    so[512 + jj]     = ce0;  so[512 + jj + 1] = ce1;
                    if (c == 0 && up == 0) so[768] = dn;
                }
            }
            asm volatile("s_waitcnt vmcnt(0)" ::: "memory");
            __syncthreads();   // bar2: hbuf stores globally complete

            // ---------------- phase P: publish flag, fetch remote slices, prefetch Gx ----------------
            if (t + 1 < LSEQ) {
                if (tid == 0) {
                    st32f(&hflags[(g * 4 + c) * 32], t + 1);
                    st32f(&cflags[(g * 4 + c) * 32], t + 1);
                }
                if (w >= 1 && w <= 3) {
                    const int c2 = (c + w) & 3;
                    const int* fl = &hflags[(g * 4 + c2) * 32];
                    int v = ld32f(fl);
                    while (v <= t) v = ld32f(fl);
                    const int row = lane >> 2, ch = lane & 3;
                    const unsigned long long* sp = (const unsigned long long*)
                        &hbuf[((((size_t)((t + 1) & 1) * 4 + g) * 4 + c2) * 16 + row) * 64 + ch * 16];
                    const unsigned long long q0 = ld64g(sp);
                    const unsigned long long q1 = ld64g(sp + 1);
                    const unsigned long long q2 = ld64g(sp + 2);
                    const unsigned long long q3 = ld64g(sp + 3);
                    char* hb = (char*)h_lds + row * 512;
                    const int base = c2 * 128 + ch * 32;
                    const int sw = (row & 7) << 4;
                    *(unsigned long long*)(hb + ((base)      ^ sw)) = q0;
                    *(unsigned long long*)(hb + ((base + 8)  ^ sw)) = q1;
                    *(unsigned long long*)(hb + ((base + 16) ^ sw)) = q2;
                    *(unsigned long long*)(hb + ((base + 24) ^ sw)) = q3;
                }
                load_gx((t + 1) & 3);
                // invariant: entering iter t+1, pflags >= min(t+3, LSEQ)
                // (producers publish at most LSEQ — clamp avoids terminal deadlock)
                const int tgt  = (t + 3 <= LSEQ) ? (t + 3) : LSEQ;
                const int pidx = (lane & 3) * 4 + g;
                int v = (lane < 4) ? ld32f(&pflags[pidx * 32]) : 0x7fffffff;
                while (__any(v < tgt)) {
                    __builtin_amdgcn_s_sleep(2);
                    v = (lane < 4) ? ld32f(&pflags[pidx * 32]) : 0x7fffffff;
                }
            }
            __syncthreads();   // bar3: h(t+1) fully in LDS
        }
    } else {
        // ===================== PRODUCER block p =====================
        const int p  = blockIdx.x - 16;   // 0..15
        const int g  = p & 3;
        const int qt = p >> 2;
        const int base_ct = qt * 24 + w * 3;
        const int nt = (qt == 3 && w == 7) ? 4 : 3;

        short8 wx[4][8];
        f32x4 bias[4];
        #pragma unroll
        for (int i = 0; i < 4; ++i) {
            if (i < nt) {
                const int ct = base_ct + i;
                if (ct == 96) {
                    const float bv = (l16 == 0) ? bdp[0] : 0.f;
                    bias[i] = f32x4{bv, bv, bv, bv};
                    #pragma unroll
                    for (int kk = 0; kk < 8; ++kk) {
                        short8 f;
                        #pragma unroll
                        for (int e = 0; e < 8; ++e)
                            f[e] = (l16 == 0) ? f2bf(Wd[kk * 32 + lhi * 8 + e]) : (short)0;
                        wx[i][kk] = f;
                    }
                } else {
                    const int gt = ct >> 4, jtg = ct & 15;
                    const float* Wg; const float* bg;
                    switch (gt) {
                        case 0: Wg = Wi;  bg = bi;  break;
                        case 1: Wg = Wf;  bg = bf;  break;
                        case 2: Wg = Wie; bg = bie; break;
                        case 3: Wg = Wfe; bg = bfe; break;
                        case 4: Wg = Wz;  bg = bz;  break;
                        default: Wg = Wo; bg = bo;  break;
                    }
                    const int col = jtg * 16 + l16;
                    const float bv = bg[col];
                    bias[i] = f32x4{bv, bv, bv, bv};
                    #pragma unroll
                    for (int kk = 0; kk < 8; ++kk) {
                        short8 f;
                        #pragma unroll
                        for (int e = 0; e < 8; ++e)
                            f[e] = f2bf(Wg[(kk * 32 + lhi * 8 + e) * 256 + col]);
                        wx[i][kk] = f;
                    }
                }
            }
        }

        const size_t xb = (size_t)(g * 16 + l16) * LSEQ;
        for (int t = 0; t < LSEQ; ++t) {
            if (t >= DEPTH) {   // back-pressure: consumers must have consumed slot
                const int cidx = g * 4 + (lane & 3);
                int v = (lane < 4) ? ld32f(&cflags[cidx * 32]) : 0x7fffffff;
                while (__any(v < t - (DEPTH - 1))) {
                    __builtin_amdgcn_s_sleep(8);
                    v = (lane < 4) ? ld32f(&cflags[cidx * 32]) : 0x7fffffff;
                }
            }
            const float* xp = x + (xb + t) * 256;
            short8 af[8];
            #pragma unroll
            for (int kk = 0; kk < 8; ++kk) {
                const f32x4 a  = *(const f32x4*)(xp + kk * 32 + lhi * 8);
                const f32x4 b2 = *(const f32x4*)(xp + kk * 32 + lhi * 8 + 4);
                short8 f;
                #pragma unroll
                for (int e = 0; e < 4; ++e) { f[e] = f2bf(a[e]); f[4 + e] = f2bf(b2[e]); }
                af[kk] = f;
            }
            f32x4 acc[4];
            #pragma unroll
            for (int i = 0; i < 4; ++i)
                if (i < nt) acc[i] = bias[i];
            #pragma unroll
            for (int kk = 0; kk < 8; ++kk) {
                #pragma unroll
                for (int i = 0; i < 4; ++i)
                    if (i < nt)
                        acc[i] = __builtin_amdgcn_mfma_f32_16x16x32_bf16(af[kk], wx[i][kk], acc[i], 0, 0, 0);
            }
            const int slot = t & (DEPTH - 1);
            #pragma unroll
            for (int i = 0; i < 4; ++i) {
                if (i < nt) {
                    const int ct = base_ct + i;
                    unsigned long long* pp =
                        (unsigned long long*)&ring[((size_t)(slot * 4 + g) * 97 + ct) * 256 + lane * 4];
                    union { unsigned long long q[2]; f32x4 v; } u;
                    u.v = acc[i];
                    st64g(pp, u.q[0]); st64g(pp + 1, u.q[1]);
                }
            }
            asm volatile("s_waitcnt vmcnt(0)" ::: "memory");
            __syncthreads();   // all waves' ring stores complete before flag
            if (tid == 0) st32f(&pflags[p * 32], t + 1);
        }
    }
}

extern "C" void kernel_launch(void* const* d_in, const int* in_sizes, int n_in,
                              void* d_out, int out_size, void* d_ws, size_t ws_size,
                              hipStream_t stream) {
    const float* x   = (const float*)d_in[0];
    const float* td  = (const float*)d_in[1];
    const float* Wi  = (const float*)d_in[2];
    const float* bi  = (const float*)d_in[3];
    const float* Wf  = (const float*)d_in[4];
    const float* bf  = (const float*)d_in[5];
    const float* Wie = (const float*)d_in[6];
    const float* bie = (const float*)d_in[7];
    const float* Wfe = (const float*)d_in[8];
    const float* bfe = (const float*)d_in[9];
    const float* Wz  = (const float*)d_in[10];
    const float* bz  = (const float*)d_in[11];
    const float* Wo  = (const float*)d_in[12];
    const float* bo  = (const float*)d_in[13];
    const float* Wd  = (const float*)d_in[14];
    const float* bd  = (const float*)d_in[15];
    const float* be  = (const float*)d_in[16];

    int* pflags = (int*)d_ws;                                // 16 * 128 B
    int* cflags = (int*)((char*)d_ws + 2048);                // 16 * 128 B
    int* hflags = (int*)((char*)d_ws + 4096);                // 16 * 128 B
    float* ring = (float*)((char*)d_ws + 8192);              // 4*4*97*256 f32 = 1.59 MB
    unsigned short* hbuf = (unsigned short*)((char*)d_ws + 8192 + 4 * 4 * 97 * 256 * 4);

    hipMemsetAsync(d_ws, 0, 8192, stream);
    hipLaunchKernelGGL(ctlstm_kernel, dim3(32), dim3(512), 0, stream,
                       x, td, Wi, bi, Wf, bf, Wie, bie, Wfe, bfe, Wz, bz, Wo, bo,
                       Wd, bd, be, (float*)d_out, pflags, cflags, hflags, ring, hbuf);
}

// Round 6
// 5429.320 us; speedup vs baseline: 5.1250x; 1.0552x over previous
//
#include <hip/hip_runtime.h>
#include <hip/hip_bf16.h>

#define LSEQ  1024
#define DEPTH 4

typedef __attribute__((ext_vector_type(8))) short short8;
typedef __attribute__((ext_vector_type(4))) float f32x4;

static __device__ __forceinline__ short f2bf(float f) {
    unsigned u = __builtin_bit_cast(unsigned, f);
    u += 0x7fffu + ((u >> 16) & 1u);
    return (short)(u >> 16);
}
static __device__ __forceinline__ float sigm(float x) { return __fdividef(1.f, 1.f + __expf(-x)); }
// tanh(g/2) = 2*sigmoid(g)-1
static __device__ __forceinline__ float tanh2(float g) { return 1.f - 2.f * __fdividef(1.f, 1.f + __expf(g)); }

static __device__ __forceinline__ void st32f(int* p, int v) { __hip_atomic_store(p, v, __ATOMIC_RELAXED, __HIP_MEMORY_SCOPE_AGENT); }
static __device__ __forceinline__ int  ld32f(const int* p) { return __hip_atomic_load(p, __ATOMIC_RELAXED, __HIP_MEMORY_SCOPE_AGENT); }
static __device__ __forceinline__ void st64g(unsigned long long* p, unsigned long long v) { __hip_atomic_store(p, v, __ATOMIC_RELAXED, __HIP_MEMORY_SCOPE_AGENT); }
static __device__ __forceinline__ unsigned long long ld64g(const unsigned long long* p) { return __hip_atomic_load(p, __ATOMIC_RELAXED, __HIP_MEMORY_SCOPE_AGENT); }

// __launch_bounds__(512, 1): HIP 2nd arg is CUDA-style min BLOCKS/CU.
// (512,2) capped VGPRs at 128 (R4: VGPR_Count=128 -> wfrag spilled, ~390MB
// scratch traffic). 1 block/CU = 2 waves/SIMD = 256-VGPR cap; occupancy is
// irrelevant (32 blocks on 256 CUs, latency-bound).
extern "C" __global__ void __launch_bounds__(512, 1)
ctlstm_kernel(const float* __restrict__ x, const float* __restrict__ td,
              const float* __restrict__ Wi, const float* __restrict__ bi,
              const float* __restrict__ Wf, const float* __restrict__ bf,
              const float* __restrict__ Wie, const float* __restrict__ bie,
              const float* __restrict__ Wfe, const float* __restrict__ bfe,
              const float* __restrict__ Wz, const float* __restrict__ bz,
              const float* __restrict__ Wo, const float* __restrict__ bo,
              const float* __restrict__ Wd, const float* __restrict__ bdp,
              const float* __restrict__ betap,
              float* __restrict__ out,
              int* __restrict__ pflags, int* __restrict__ cflags,
              int* __restrict__ hflags, float* __restrict__ ring,
              unsigned short* __restrict__ hbuf)
{
    const int tid  = threadIdx.x;
    const int w    = tid >> 6;      // wave 0..7
    const int lane = tid & 63;
    const int l16  = lane & 15;
    const int lhi  = lane >> 4;

    if (blockIdx.x < 16) {
        // ===================== CONSUMER block (g, c) =====================
        const int g = blockIdx.x >> 2;
        const int c = blockIdx.x & 3;

        // [24][17][18]: mid-dim padded so tile stride = 306 dwords (== 18 mod 32);
        // R4's 288 (== 0 mod 32) made the U-phase float2 gate reads a 4-way
        // bank conflict (11.3M SQ_LDS_BANK_CONFLICT).
        __shared__ float g_lds[24][17][18];                      // [T=gt*4+jt][row][col]
        __shared__ __align__(16) unsigned short h_lds[16 * 256]; // 8 KB, XOR-swizzled rows
        __shared__ float dvals[16];

        ((unsigned long long*)h_lds)[tid]       = 0ull;
        ((unsigned long long*)h_lds)[tid + 512] = 0ull;

        const float beta = betap[0];

        // ---- resident weight fragments (h-part, rows 256..511) ----
        short8 wfrag[4][8];
        #pragma unroll
        for (int i = 0; i < 4; ++i) {
            const bool hav = (i < 3) || (w == 7);
            if (hav) {
                if (i == 3) {
                    #pragma unroll
                    for (int kk = 0; kk < 8; ++kk) {
                        short8 f;
                        #pragma unroll
                        for (int e = 0; e < 8; ++e)
                            f[e] = (l16 == 0) ? f2bf(Wd[256 + kk * 32 + lhi * 8 + e]) : (short)0;
                        wfrag[i][kk] = f;
                    }
                } else {
                    const int T = w * 3 + i, gt = T >> 2, jt = T & 3;
                    const float* Wg;
                    switch (gt) {
                        case 0: Wg = Wi;  break;
                        case 1: Wg = Wf;  break;
                        case 2: Wg = Wie; break;
                        case 3: Wg = Wfe; break;
                        case 4: Wg = Wz;  break;
                        default: Wg = Wo; break;
                    }
                    const int col = c * 64 + jt * 16 + l16;
                    #pragma unroll
                    for (int kk = 0; kk < 8; ++kk) {
                        short8 f;
                        #pragma unroll
                        for (int e = 0; e < 8; ++e)
                            f[e] = f2bf(Wg[(256 + kk * 32 + lhi * 8 + e) * 256 + col]);
                        wfrag[i][kk] = f;
                    }
                }
            }
        }

        // update-phase mapping: this thread owns (row urow, cols c*64+2*up..+1)
        const int urow = tid >> 5;
        const int up   = tid & 31;
        float cC[2]  = {0.f, 0.f};
        float ceS[2] = {0.f, 0.f};
        float h2[2]  = {0.f, 0.f};

        f32x4 gx[4];
        auto load_gx = [&](int slot) {
            #pragma unroll
            for (int i = 0; i < 4; ++i) {
                const bool hav = (i < 3) || (w == 7);
                if (hav) {
                    const int T  = w * 3 + i;
                    const int ct = (i == 3) ? 96 : ((T >> 2) * 16 + c * 4 + (T & 3));
                    const unsigned long long* pp =
                        (const unsigned long long*)&ring[((size_t)(slot * 4 + g) * 97 + ct) * 256 + lane * 4];
                    union { unsigned long long q[2]; f32x4 v; } u;
                    u.q[0] = ld64g(pp); u.q[1] = ld64g(pp + 1);
                    gx[i] = u.v;
                }
            }
        };

        // prologue: producers must have finished steps 0 and 1
        {
            const int pidx = (lane & 3) * 4 + g;
            int v = (lane < 4) ? ld32f(&pflags[pidx * 32]) : 0x7fffffff;
            while (__any(v < 2)) {
                __builtin_amdgcn_s_sleep(8);
                v = (lane < 4) ? ld32f(&pflags[pidx * 32]) : 0x7fffffff;
            }
        }
        load_gx(0);
        __syncthreads();

        for (int t = 0; t < LSEQ; ++t) {
            // ---------------- phase G: recurrent GEMM + activations ----------------
            short8 hf[8];
            #pragma unroll
            for (int kk = 0; kk < 8; ++kk) {
                const int bo = l16 * 512 + ((kk * 64 + lhi * 16) ^ ((l16 & 7) << 4));
                hf[kk] = *(const short8*)((const char*)h_lds + bo);
            }
            f32x4 acc[4];
            #pragma unroll
            for (int i = 0; i < 4; ++i)
                if ((i < 3) || (w == 7)) acc[i] = gx[i];
            #pragma unroll
            for (int kk = 0; kk < 8; ++kk) {
                #pragma unroll
                for (int i = 0; i < 4; ++i)
                    if ((i < 3) || (w == 7))
                        acc[i] = __builtin_amdgcn_mfma_f32_16x16x32_bf16(hf[kk], wfrag[i][kk], acc[i], 0, 0, 0);
            }
            #pragma unroll
            for (int i = 0; i < 3; ++i) {
                const int T = w * 3 + i, gt = T >> 2;
                #pragma unroll
                for (int q = 0; q < 4; ++q) {
                    float v = acc[i][q];
                    v = (gt == 4) ? tanh2(v) : sigm(v);
                    g_lds[T][lhi * 4 + q][l16] = v;
                }
            }
            if (w == 7 && l16 == 0) {
                #pragma unroll
                for (int q = 0; q < 4; ++q) {
                    const float bg_ = beta * acc[3][q];
                    const float sp  = fmaxf(bg_, 0.f) + __logf(1.f + __expf(-fabsf(bg_)));
                    dvals[lhi * 4 + q] = __fdividef(sp, beta);
                }
            }
            __syncthreads();   // bar1: gates ready

            // ---------------- phase U: state update (own 64-col slice) ----------------
            {
                const int jtl = up >> 3;
                const int cc2 = (up & 7) * 2;
                const float2 iv  = *(const float2*)&g_lds[0 * 4 + jtl][urow][cc2];
                const float2 fv  = *(const float2*)&g_lds[1 * 4 + jtl][urow][cc2];
                const float2 iev = *(const float2*)&g_lds[2 * 4 + jtl][urow][cc2];
                const float2 fev = *(const float2*)&g_lds[3 * 4 + jtl][urow][cc2];
                const float2 zv  = *(const float2*)&g_lds[4 * 4 + jtl][urow][cc2];
                const float2 ov  = *(const float2*)&g_lds[5 * 4 + jtl][urow][cc2];
                const float dn = dvals[urow];

                // outputs[:, t, :] = h(t)
                *(float2*)(out + ((size_t)(g * 16 + urow) * LSEQ + t) * 256 + c * 64 + up * 2)
                    = make_float2(h2[0], h2[1]);

                const float cs0 = fv.x * cC[0] + iv.x * zv.x;
                const float cs1 = fv.y * cC[1] + iv.y * zv.y;
                const float ce0 = fev.x * ceS[0] + iev.x * zv.x;
                const float ce1 = fev.y * ceS[1] + iev.y * zv.y;

                if (t + 1 < LSEQ) {
                    const float dtv = td[(size_t)(g * 16 + urow) * LSEQ + (t + 1)];
                    const float e   = __expf(-dn * dtv);
                    const float cn0 = cs0 + (ce0 - cs0) * e;
                    const float cn1 = cs1 + (ce1 - cs1) * e;
                    const float hv0 = ov.x * tanh2(2.f * cn0);
                    const float hv1 = ov.y * tanh2(2.f * cn1);
                    cC[0] = cn0; cC[1] = cn1;
                    ceS[0] = ce0; ceS[1] = ce1;
                    h2[0] = hv0; h2[1] = hv1;
                    const unsigned pk = (unsigned)(unsigned short)f2bf(hv0)
                                      | ((unsigned)(unsigned short)f2bf(hv1) << 16);
                    const int par = (t + 1) & 1;
                    st32f((int*)&hbuf[((((size_t)par * 4 + g) * 4 + c) * 16 + urow) * 64 + up * 2], (int)pk);
                    const int lin = c * 128 + up * 4;
                    *(unsigned*)((char*)h_lds + urow * 512 + (lin ^ ((urow & 7) << 4))) = pk;
                } else {
                    float* so = out + (size_t)64 * LSEQ * 256 + (size_t)(g * 16 + urow) * 769;
                    const int jj = c * 64 + up * 2;
                    so[jj]           = ov.x; so[jj + 1]       = ov.y;
                    so[256 + jj]     = cs0;  so[256 + jj + 1] = cs1;
                    so[512 + jj]     = ce0;  so[512 + jj + 1] = ce1;
                    if (c == 0 && up == 0) so[768] = dn;
                }
            }
            asm volatile("s_waitcnt vmcnt(0)" ::: "memory");
            __syncthreads();   // bar2: hbuf stores globally complete

            // ---------------- phase P: publish flag, fetch remote slices, prefetch Gx ----------------
            if (t + 1 < LSEQ) {
                if (tid == 0) {
                    st32f(&hflags[(g * 4 + c) * 32], t + 1);
                    st32f(&cflags[(g * 4 + c) * 32], t + 1);
                }
                if (w >= 1 && w <= 3) {
                    const int c2 = (c + w) & 3;
                    const int* fl = &hflags[(g * 4 + c2) * 32];
                    int v = ld32f(fl);
                    while (v <= t) v = ld32f(fl);
                    const int row = lane >> 2, ch = lane & 3;
                    const unsigned long long* sp = (const unsigned long long*)
                        &hbuf[((((size_t)((t + 1) & 1) * 4 + g) * 4 + c2) * 16 + row) * 64 + ch * 16];
                    const unsigned long long q0 = ld64g(sp);
                    const unsigned long long q1 = ld64g(sp + 1);
                    const unsigned long long q2 = ld64g(sp + 2);
                    const unsigned long long q3 = ld64g(sp + 3);
                    char* hb = (char*)h_lds + row * 512;
                    const int base = c2 * 128 + ch * 32;
                    const int sw = (row & 7) << 4;
                    *(unsigned long long*)(hb + ((base)      ^ sw)) = q0;
                    *(unsigned long long*)(hb + ((base + 8)  ^ sw)) = q1;
                    *(unsigned long long*)(hb + ((base + 16) ^ sw)) = q2;
                    *(unsigned long long*)(hb + ((base + 24) ^ sw)) = q3;
                }
                load_gx((t + 1) & 3);
                // invariant: entering iter t+1, pflags >= min(t+3, LSEQ)
                // (producers publish at most LSEQ — clamp avoids terminal deadlock)
                const int tgt  = (t + 3 <= LSEQ) ? (t + 3) : LSEQ;
                const int pidx = (lane & 3) * 4 + g;
                int v = (lane < 4) ? ld32f(&pflags[pidx * 32]) : 0x7fffffff;
                while (__any(v < tgt)) {
                    __builtin_amdgcn_s_sleep(2);
                    v = (lane < 4) ? ld32f(&pflags[pidx * 32]) : 0x7fffffff;
                }
            }
            __syncthreads();   // bar3: h(t+1) fully in LDS
        }
    } else {
        // ===================== PRODUCER block p =====================
        const int p  = blockIdx.x - 16;   // 0..15
        const int g  = p & 3;
        const int qt = p >> 2;
        const int base_ct = qt * 24 + w * 3;
        const int nt = (qt == 3 && w == 7) ? 4 : 3;

        short8 wx[4][8];
        f32x4 bias[4];
        #pragma unroll
        for (int i = 0; i < 4; ++i) {
            if (i < nt) {
                const int ct = base_ct + i;
                if (ct == 96) {
                    const float bv = (l16 == 0) ? bdp[0] : 0.f;
                    bias[i] = f32x4{bv, bv, bv, bv};
                    #pragma unroll
                    for (int kk = 0; kk < 8; ++kk) {
                        short8 f;
                        #pragma unroll
                        for (int e = 0; e < 8; ++e)
                            f[e] = (l16 == 0) ? f2bf(Wd[kk * 32 + lhi * 8 + e]) : (short)0;
                        wx[i][kk] = f;
                    }
                } else {
                    const int gt = ct >> 4, jtg = ct & 15;
                    const float* Wg; const float* bg;
                    switch (gt) {
                        case 0: Wg = Wi;  bg = bi;  break;
                        case 1: Wg = Wf;  bg = bf;  break;
                        case 2: Wg = Wie; bg = bie; break;
                        case 3: Wg = Wfe; bg = bfe; break;
                        case 4: Wg = Wz;  bg = bz;  break;
                        default: Wg = Wo; bg = bo;  break;
                    }
                    const int col = jtg * 16 + l16;
                    const float bv = bg[col];
                    bias[i] = f32x4{bv, bv, bv, bv};
                    #pragma unroll
                    for (int kk = 0; kk < 8; ++kk) {
                        short8 f;
                        #pragma unroll
                        for (int e = 0; e < 8; ++e)
                            f[e] = f2bf(Wg[(kk * 32 + lhi * 8 + e) * 256 + col]);
                        wx[i][kk] = f;
                    }
                }
            }
        }

        const size_t xb = (size_t)(g * 16 + l16) * LSEQ;
        for (int t = 0; t < LSEQ; ++t) {
            if (t >= DEPTH) {   // back-pressure: consumers must have consumed slot
                const int cidx = g * 4 + (lane & 3);
                int v = (lane < 4) ? ld32f(&cflags[cidx * 32]) : 0x7fffffff;
                while (__any(v < t - (DEPTH - 1))) {
                    __builtin_amdgcn_s_sleep(8);
                    v = (lane < 4) ? ld32f(&cflags[cidx * 32]) : 0x7fffffff;
                }
            }
            const float* xp = x + (xb + t) * 256;
            short8 af[8];
            #pragma unroll
            for (int kk = 0; kk < 8; ++kk) {
                const f32x4 a  = *(const f32x4*)(xp + kk * 32 + lhi * 8);
                const f32x4 b2 = *(const f32x4*)(xp + kk * 32 + lhi * 8 + 4);
                short8 f;
                #pragma unroll
                for (int e = 0; e < 4; ++e) { f[e] = f2bf(a[e]); f[4 + e] = f2bf(b2[e]); }
                af[kk] = f;
            }
            f32x4 acc[4];
            #pragma unroll
            for (int i = 0; i < 4; ++i)
                if (i < nt) acc[i] = bias[i];
            #pragma unroll
            for (int kk = 0; kk < 8; ++kk) {
                #pragma unroll
                for (int i = 0; i < 4; ++i)
                    if (i < nt)
                        acc[i] = __builtin_amdgcn_mfma_f32_16x16x32_bf16(af[kk], wx[i][kk], acc[i], 0, 0, 0);
            }
            const int slot = t & (DEPTH - 1);
            #pragma unroll
            for (int i = 0; i < 4; ++i) {
                if (i < nt) {
                    const int ct = base_ct + i;
                    unsigned long long* pp =
                        (unsigned long long*)&ring[((size_t)(slot * 4 + g) * 97 + ct) * 256 + lane * 4];
                    union { unsigned long long q[2]; f32x4 v; } u;
                    u.v = acc[i];
                    st64g(pp, u.q[0]); st64g(pp + 1, u.q[1]);
                }
            }
            asm volatile("s_waitcnt vmcnt(0)" ::: "memory");
            __syncthreads();   // all waves' ring stores complete before flag
            if (tid == 0) st32f(&pflags[p * 32], t + 1);
        }
    }
}

extern "C" void kernel_launch(void* const* d_in, const int* in_sizes, int n_in,
                              void* d_out, int out_size, void* d_ws, size_t ws_size,
                              hipStream_t stream) {
    const float* x   = (const float*)d_in[0];
    const float* td  = (const float*)d_in[1];
    const float* Wi  = (const float*)d_in[2];
    const float* bi  = (const float*)d_in[3];
    const float* Wf  = (const float*)d_in[4];
    const float* bf  = (const float*)d_in[5];
    const float* Wie = (const float*)d_in[6];
    const float* bie = (const float*)d_in[7];
    const float* Wfe = (const float*)d_in[8];
    const float* bfe = (const float*)d_in[9];
    const float* Wz  = (const float*)d_in[10];
    const float* bz  = (const float*)d_in[11];
    const float* Wo  = (const float*)d_in[12];
    const float* bo  = (const float*)d_in[13];
    const float* Wd  = (const float*)d_in[14];
    const float* bd  = (const float*)d_in[15];
    const float* be  = (const float*)d_in[16];

    int* pflags = (int*)d_ws;                                // 16 * 128 B
    int* cflags = (int*)((char*)d_ws + 2048);                // 16 * 128 B
    int* hflags = (int*)((char*)d_ws + 4096);                // 16 * 128 B
    float* ring = (float*)((char*)d_ws + 8192);              // 4*4*97*256 f32 = 1.59 MB
    unsigned short* hbuf = (unsigned short*)((char*)d_ws + 8192 + 4 * 4 * 97 * 256 * 4);

    hipMemsetAsync(d_ws, 0, 8192, stream);
    hipLaunchKernelGGL(ctlstm_kernel, dim3(32), dim3(512), 0, stream,
                       x, td, Wi, bi, Wf, bf, Wie, bie, Wfe, bfe, Wz, bz, Wo, bo,
                       Wd, bd, be, (float*)d_out, pflags, cflags, hflags, ring, hbuf);
}